// Round 9
// baseline (455.902 us; speedup 1.0000x reference)
//
#include <hip/hip_runtime.h>
#include <cmath>

#define TT 1024
#define BB 8

typedef __attribute__((ext_vector_type(4))) float f4;
typedef __attribute__((ext_vector_type(4))) unsigned int u4;
typedef __attribute__((ext_vector_type(8))) short s8v;

__device__ __forceinline__ ushort f2bf(float x) {
  unsigned u = __builtin_bit_cast(unsigned, x);
  unsigned r = (u + 0x7FFFu + ((u >> 16) & 1u)) >> 16;
  return (ushort)r;
}
__device__ __forceinline__ float bf2f(ushort b) {
  unsigned u = ((unsigned)b) << 16;
  return __builtin_bit_cast(float, u);
}
__device__ __forceinline__ void st8(ushort* p, const ushort* v) {
  u4 w;
  w.x = (unsigned)v[0] | ((unsigned)v[1] << 16);
  w.y = (unsigned)v[2] | ((unsigned)v[3] << 16);
  w.z = (unsigned)v[4] | ((unsigned)v[5] << 16);
  w.w = (unsigned)v[6] | ((unsigned)v[7] << 16);
  *(u4*)p = w;
}

// ---------------- K1: x @ {Wq/16, Wk, Wv} -> transposed bf16 hi/lo + vT ----------------
// grid 512: b=bid&7, 16-token tiles. 2 waves/EU min.
__global__ __launch_bounds__(256, 2) void k_xw(
    const float* __restrict__ x, const float* __restrict__ Wq,
    const float* __restrict__ Wk, const float* __restrict__ Wv,
    ushort* __restrict__ xTqhi, ushort* __restrict__ xTqlo,
    ushort* __restrict__ xTkhi, ushort* __restrict__ xTklo,
    ushort* __restrict__ vT) {
  __shared__ float xs[16][256];
  int bid = blockIdx.x;
  int b = bid & 7, t0 = (bid >> 3) * 16;
  int tid = threadIdx.x;
#pragma unroll
  for (int i = 0; i < 4; ++i) {
    int e = i * 256 + tid;
    int t = e >> 6, c4 = (e & 63) * 4;
    *(f4*)&xs[t][c4] = *(const f4*)&x[((size_t)(b * 1024 + t0 + t)) * 256 + c4];
  }
  int c = tid, h = c >> 5, d = c & 31;
  float wqr[32], wkr[32], wvr[32];
#pragma unroll
  for (int e = 0; e < 32; ++e) {
    wqr[e] = Wq[e * 32 + d] * 0.0625f;  // fold scale = dim^-0.5 = 1/16 into Wq
    wkr[e] = Wk[e * 32 + d];
    wvr[e] = Wv[e * 32 + d];
  }
  __syncthreads();
  size_t rowq = ((size_t)(b * 256 + c)) * 1024 + t0;
#pragma unroll
  for (int tg = 0; tg < 2; ++tg) {
    ushort qh[8], ql[8], kh[8], kl[8], vh[8];
#pragma unroll
    for (int tt = 0; tt < 8; ++tt) {
      int t = tg * 8 + tt;
      float aq = 0.f, ak = 0.f, av = 0.f;
#pragma unroll
      for (int e = 0; e < 32; ++e) {
        float xe = xs[t][h * 32 + e];
        aq = fmaf(xe, wqr[e], aq);
        ak = fmaf(xe, wkr[e], ak);
        av = fmaf(xe, wvr[e], av);
      }
      ushort hq = f2bf(aq); qh[tt] = hq; ql[tt] = f2bf(aq - bf2f(hq));
      ushort hk = f2bf(ak); kh[tt] = hk; kl[tt] = f2bf(ak - bf2f(hk));
      vh[tt] = f2bf(av);
    }
    st8(xTqhi + rowq + tg * 8, qh);
    st8(xTqlo + rowq + tg * 8, ql);
    st8(xTkhi + rowq + tg * 8, kh);
    st8(xTklo + rowq + tg * 8, kl);
    st8(vT    + rowq + tg * 8, vh);
  }
}

// ---------------- K2: GCN [q|k] = adj @ [xq|xk] via MFMA, grid 512 ----------------
__global__ __launch_bounds__(256, 2) void k_gcn(
    const int* __restrict__ adj,
    const ushort* __restrict__ xTqhi, const ushort* __restrict__ xTqlo,
    const ushort* __restrict__ xTkhi, const ushort* __restrict__ xTklo,
    ushort* __restrict__ qhi, ushort* __restrict__ qlo,
    ushort* __restrict__ khi, ushort* __restrict__ klo) {
  int bid = blockIdx.x;
  int ct = bid & 3, lt = ((bid >> 2) & 15) * 64, b = bid >> 6;
  int nt = ct >> 1, cbase = (ct & 1) * 128;
  const ushort* XH = (nt ? xTkhi : xTqhi) + (size_t)b * 256 * 1024;
  const ushort* XL = (nt ? xTklo : xTqlo) + (size_t)b * 256 * 1024;
  ushort* OH = (nt ? khi : qhi) + (size_t)b * 1024 * 256;
  ushort* OL = (nt ? klo : qlo) + (size_t)b * 1024 * 256;
  const int* AD = adj + (size_t)b * 1024 * 1024;
  int tid = threadIdx.x, wid = tid >> 6, lane = tid & 63;
  int lrow = lane & 15, lk = lane >> 4;
  int wr = wid >> 1, wc = wid & 1;
  int rbase = lt + wr * 32;
  int cb2 = cbase + wc * 64;
  f4 acc[2][4];
#pragma unroll
  for (int i = 0; i < 2; ++i)
#pragma unroll
    for (int j = 0; j < 4; ++j) acc[i][j] = (f4)(0.f);

  for (int k0 = 0; k0 < 1024; k0 += 32) {
    s8v afr[2];
#pragma unroll
    for (int rq = 0; rq < 2; ++rq) {
      const int* ap = &AD[(size_t)(rbase + rq * 16 + lrow) * 1024 + k0 + lk * 8];
      int4 a0 = *(const int4*)ap;
      int4 a1 = *(const int4*)(ap + 4);
      u4 fw;
      fw.x = (a0.x ? 0x3F80u : 0u) | (a0.y ? 0x3F800000u : 0u);
      fw.y = (a0.z ? 0x3F80u : 0u) | (a0.w ? 0x3F800000u : 0u);
      fw.z = (a1.x ? 0x3F80u : 0u) | (a1.y ? 0x3F800000u : 0u);
      fw.w = (a1.z ? 0x3F80u : 0u) | (a1.w ? 0x3F800000u : 0u);
      afr[rq] = __builtin_bit_cast(s8v, fw);
    }
#pragma unroll
    for (int nq = 0; nq < 4; ++nq) {
      int col = cb2 + nq * 16 + lrow;
      s8v bh = *(const s8v*)&XH[(size_t)col * 1024 + k0 + lk * 8];
      s8v bl = *(const s8v*)&XL[(size_t)col * 1024 + k0 + lk * 8];
#pragma unroll
      for (int rq = 0; rq < 2; ++rq) {
        acc[rq][nq] = __builtin_amdgcn_mfma_f32_16x16x32_bf16(afr[rq], bh, acc[rq][nq], 0, 0, 0);
        acc[rq][nq] = __builtin_amdgcn_mfma_f32_16x16x32_bf16(afr[rq], bl, acc[rq][nq], 0, 0, 0);
      }
    }
  }
#pragma unroll
  for (int rq = 0; rq < 2; ++rq)
#pragma unroll
    for (int nq = 0; nq < 4; ++nq)
#pragma unroll
      for (int e = 0; e < 4; ++e) {
        float v = acc[rq][nq][e];
        int row = rbase + rq * 16 + lk * 4 + e;
        int col = cb2 + nq * 16 + lrow;
        ushort hi = f2bf(v);
        ushort lo = f2bf(v - bf2f(hi));
        OH[(size_t)row * 256 + col] = hi;
        OL[(size_t)row * 256 + col] = lo;
      }
}

// ---------------- K3a: score stats, grid 2048 (b x 32 row-tiles x 8 col-chunks) --------
__global__ __launch_bounds__(256, 2) void k_stats(
    const ushort* __restrict__ qhi, const ushort* __restrict__ qlo,
    const ushort* __restrict__ khi, const ushort* __restrict__ klo,
    const int* __restrict__ adj, const float* __restrict__ Lam,
    float* __restrict__ pm, float* __restrict__ ps) {
  __shared__ float sm_m[2][32][8];
  __shared__ float sm_s[2][32][8];
  int bid = blockIdx.x;
  int b = bid >> 8;
  int lt = ((bid >> 3) & 31) << 5;
  int tc = bid & 7;
  int tid = threadIdx.x, wid = tid >> 6, lane = tid & 63;
  int lrow = lane & 15, lk = lane >> 4;
  int wr = wid >> 1, wc = wid & 1;
  const ushort* QH = qhi + (size_t)b * 1024 * 256;
  const ushort* QL = qlo + (size_t)b * 1024 * 256;
  const ushort* KH = khi + (size_t)b * 1024 * 256;
  const ushort* KL = klo + (size_t)b * 1024 * 256;
  const int* AD = adj + (size_t)b * 1024 * 1024;

  s8v qfh[8], qfl[8];
  int qrow = lt + wr * 16 + lrow;
#pragma unroll
  for (int h = 0; h < 8; ++h) {
    qfh[h] = *(const s8v*)&QH[(size_t)qrow * 256 + h * 32 + lk * 8];
    qfl[h] = *(const s8v*)&QL[(size_t)qrow * 256 + h * 32 + lk * 8];
  }
  float ms[4][8], ss[4][8];
#pragma unroll
  for (int e = 0; e < 4; ++e)
#pragma unroll
    for (int i2 = 0; i2 < 8; ++i2) { ms[e][i2] = -3.0e38f; ss[e][i2] = 0.f; }

  for (int it = 0; it < 4; ++it) {
    int t0 = tc * 128 + (it * 2 + wc) * 16;
    f4 acc[8];
#pragma unroll
    for (int h = 0; h < 8; ++h) {
      s8v kh = *(const s8v*)&KH[(size_t)(t0 + lrow) * 256 + h * 32 + lk * 8];
      s8v kl = *(const s8v*)&KL[(size_t)(t0 + lrow) * 256 + h * 32 + lk * 8];
      f4 a = (f4)(0.f);
      a = __builtin_amdgcn_mfma_f32_16x16x32_bf16(qfh[h], kh, a, 0, 0, 0);
      a = __builtin_amdgcn_mfma_f32_16x16x32_bf16(qfh[h], kl, a, 0, 0, 0);
      a = __builtin_amdgcn_mfma_f32_16x16x32_bf16(qfl[h], kh, a, 0, 0, 0);
      acc[h] = a;
    }
#pragma unroll
    for (int e = 0; e < 4; ++e) {
      int row = lt + wr * 16 + lk * 4 + e;
      int a = AD[(size_t)row * 1024 + t0 + lrow];
      bool pred = a > 0;
      float raw[8];
#pragma unroll
      for (int h = 0; h < 8; ++h) { float v = acc[h][e]; raw[h] = fmaxf(v, 0.01f * v); }
#pragma unroll
      for (int i2 = 0; i2 < 8; ++i2) {
        float s = 0.f;
#pragma unroll
        for (int j = 0; j < 8; ++j) s = fmaf(Lam[i2 * 8 + j], raw[j], s);
        float d = s - ms[e][i2];
        float ex = __expf(fminf(d, -d));
        float snew = (d > 0.f) ? fmaf(ss[e][i2], ex, 1.f) : (ss[e][i2] + ex);
        float mnew = fmaxf(ms[e][i2], s);
        if (pred) { ss[e][i2] = snew; ms[e][i2] = mnew; }
      }
    }
  }
  // reduce across the 16 col-lanes (bits 0..3 of lane)
#pragma unroll
  for (int e = 0; e < 4; ++e)
#pragma unroll
    for (int i2 = 0; i2 < 8; ++i2) {
      float mm = ms[e][i2], sv = ss[e][i2];
      for (int off = 1; off < 16; off <<= 1) {
        float om = __shfl_xor(mm, off, 64);
        float os = __shfl_xor(sv, off, 64);
        float d = mm - om;
        float ex = __expf(fminf(d, -d));
        float sA = fmaf(os, ex, sv);
        float sB = fmaf(sv, ex, os);
        sv = (d >= 0.f) ? sA : sB;
        mm = fmaxf(mm, om);
      }
      ms[e][i2] = mm; ss[e][i2] = sv;
    }
  if (lrow == 0) {
#pragma unroll
    for (int e = 0; e < 4; ++e)
#pragma unroll
      for (int i2 = 0; i2 < 8; ++i2) {
        sm_m[wc][wr * 16 + lk * 4 + e][i2] = ms[e][i2];
        sm_s[wc][wr * 16 + lk * 4 + e][i2] = ss[e][i2];
      }
  }
  __syncthreads();
  {
    int rw = tid >> 3, i2 = tid & 7;
    float m0 = sm_m[0][rw][i2], m1 = sm_m[1][rw][i2];
    float s0 = sm_s[0][rw][i2], s1 = sm_s[1][rw][i2];
    float M = fmaxf(m0, m1);
    float S = s0 * __expf(m0 - M) + s1 * __expf(m1 - M);
    size_t R = ((size_t)(b * 8 + i2) * 1024 + lt + rw);
    pm[R * 8 + tc] = M;
    ps[R * 8 + tc] = S;
  }
}

// ---------------- K3b: reduce 8 chunk-partials -> (m, 1/sum) per row ----------------
__global__ __launch_bounds__(256) void k_reduce(
    const float* __restrict__ pm, const float* __restrict__ ps,
    float* __restrict__ fm, float* __restrict__ fr) {
  int R = blockIdx.x * 256 + threadIdx.x;   // 65536 rows
  f4 m0 = *(const f4*)&pm[(size_t)R * 8];
  f4 m1 = *(const f4*)&pm[(size_t)R * 8 + 4];
  f4 s0 = *(const f4*)&ps[(size_t)R * 8];
  f4 s1 = *(const f4*)&ps[(size_t)R * 8 + 4];
  float M = fmaxf(fmaxf(fmaxf(m0.x, m0.y), fmaxf(m0.z, m0.w)),
                  fmaxf(fmaxf(m1.x, m1.y), fmaxf(m1.z, m1.w)));
  float S = s0.x * __expf(m0.x - M) + s0.y * __expf(m0.y - M) +
            s0.z * __expf(m0.z - M) + s0.w * __expf(m0.w - M) +
            s1.x * __expf(m1.x - M) + s1.y * __expf(m1.y - M) +
            s1.z * __expf(m1.z - M) + s1.w * __expf(m1.w - M);
  fm[R] = M;
  fr[R] = 1.f / S;
}

// ---------------- K3c: recompute scores + write final softmax p, grid 2048 ----------
__global__ __launch_bounds__(256, 2) void k_final(
    const ushort* __restrict__ qhi, const ushort* __restrict__ qlo,
    const ushort* __restrict__ khi, const ushort* __restrict__ klo,
    const int* __restrict__ adj, const float* __restrict__ Lam,
    const float* __restrict__ fm, const float* __restrict__ fr,
    float* __restrict__ attn) {
  __shared__ float fin_m[32][8];
  __shared__ float fin_r[32][8];
  int bid = blockIdx.x;
  int b = bid >> 8;
  int lt = ((bid >> 3) & 31) << 5;
  int tc = bid & 7;
  int tid = threadIdx.x, wid = tid >> 6, lane = tid & 63;
  int lrow = lane & 15, lk = lane >> 4;
  int wr = wid >> 1, wc = wid & 1;
  const ushort* QH = qhi + (size_t)b * 1024 * 256;
  const ushort* QL = qlo + (size_t)b * 1024 * 256;
  const ushort* KH = khi + (size_t)b * 1024 * 256;
  const ushort* KL = klo + (size_t)b * 1024 * 256;
  const int* AD = adj + (size_t)b * 1024 * 1024;
  float* AT = attn + (size_t)b * 8 * 1024 * 1024;
  {
    int rw = tid >> 3, i2 = tid & 7;
    size_t R = ((size_t)(b * 8 + i2) * 1024 + lt + rw);
    fin_m[rw][i2] = fm[R];
    fin_r[rw][i2] = fr[R];
  }
  s8v qfh[8], qfl[8];
  int qrow = lt + wr * 16 + lrow;
#pragma unroll
  for (int h = 0; h < 8; ++h) {
    qfh[h] = *(const s8v*)&QH[(size_t)qrow * 256 + h * 32 + lk * 8];
    qfl[h] = *(const s8v*)&QL[(size_t)qrow * 256 + h * 32 + lk * 8];
  }
  __syncthreads();
  float ms[4][8], rs[4][8];
#pragma unroll
  for (int e = 0; e < 4; ++e)
#pragma unroll
    for (int i2 = 0; i2 < 8; ++i2) {
      ms[e][i2] = fin_m[wr * 16 + lk * 4 + e][i2];
      rs[e][i2] = fin_r[wr * 16 + lk * 4 + e][i2];
    }
  for (int it = 0; it < 4; ++it) {
    int t0 = tc * 128 + (it * 2 + wc) * 16;
    f4 acc[8];
#pragma unroll
    for (int h = 0; h < 8; ++h) {
      s8v kh = *(const s8v*)&KH[(size_t)(t0 + lrow) * 256 + h * 32 + lk * 8];
      s8v kl = *(const s8v*)&KL[(size_t)(t0 + lrow) * 256 + h * 32 + lk * 8];
      f4 a = (f4)(0.f);
      a = __builtin_amdgcn_mfma_f32_16x16x32_bf16(qfh[h], kh, a, 0, 0, 0);
      a = __builtin_amdgcn_mfma_f32_16x16x32_bf16(qfh[h], kl, a, 0, 0, 0);
      a = __builtin_amdgcn_mfma_f32_16x16x32_bf16(qfl[h], kh, a, 0, 0, 0);
      acc[h] = a;
    }
#pragma unroll
    for (int e = 0; e < 4; ++e) {
      int row = lt + wr * 16 + lk * 4 + e;
      int a = AD[(size_t)row * 1024 + t0 + lrow];
      bool pred = a > 0;
      float raw[8];
#pragma unroll
      for (int h = 0; h < 8; ++h) { float v = acc[h][e]; raw[h] = fmaxf(v, 0.01f * v); }
#pragma unroll
      for (int i2 = 0; i2 < 8; ++i2) {
        float s = 0.f;
#pragma unroll
        for (int j = 0; j < 8; ++j) s = fmaf(Lam[i2 * 8 + j], raw[j], s);
        float p = pred ? __expf(s - ms[e][i2]) * rs[e][i2] : 0.f;
        AT[((size_t)i2 * 1024 + row) * 1024 + t0 + lrow] = p;
      }
    }
  }
}

// ---------------- K4: PV via bf16 MFMA + GELU -> g ----------------
__global__ __launch_bounds__(256, 4) void k_pv(
    const float* __restrict__ attn, const ushort* __restrict__ vT,
    float* __restrict__ g) {
  __shared__ ushort Vs[32][136];
  __shared__ unsigned pt[64 * 128 / 2];
  int bid = blockIdx.x;
  int b = bid & 7, h = (bid >> 3) & 7, lt = (bid >> 6) * 64;
  int tid = threadIdx.x, wid = tid >> 6, lane = tid & 63;
  int lrow = lane & 15, lk = lane >> 4;
  const float* AT = attn + ((size_t)(b * 8 + h) * 1024 + lt) * 1024;
  const ushort* VTb = vT + (size_t)(b * 256 + h * 32) * 1024;
  char* ptb = (char*)pt;
  f4 acc[2];
  acc[0] = (f4)(0.f); acc[1] = (f4)(0.f);

  for (int tc = 0; tc < 1024; tc += 128) {
    {
      int col = tid >> 3, toff = (tid & 7) * 16;
      u4 v0 = *(const u4*)&VTb[(size_t)col * 1024 + tc + toff];
      u4 v1 = *(const u4*)&VTb[(size_t)col * 1024 + tc + toff + 8];
      *(u4*)&Vs[col][toff] = v0;
      *(u4*)&Vs[col][toff + 8] = v1;
    }
    {
      int row = tid >> 2, tq = (tid & 3) * 32;
      const float* src = &AT[(size_t)row * 1024 + tc + tq];
#pragma unroll
      for (int i = 0; i < 4; ++i) {
        f4 p0 = *(const f4*)&src[i * 8];
        f4 p1 = *(const f4*)&src[i * 8 + 4];
        u4 pk;
        pk.x = (unsigned)f2bf(p0[0]) | ((unsigned)f2bf(p0[1]) << 16);
        pk.y = (unsigned)f2bf(p0[2]) | ((unsigned)f2bf(p0[3]) << 16);
        pk.z = (unsigned)f2bf(p1[0]) | ((unsigned)f2bf(p1[1]) << 16);
        pk.w = (unsigned)f2bf(p1[2]) | ((unsigned)f2bf(p1[3]) << 16);
        int t = tq + i * 8;
        int boff = row * 256 + ((t * 2) ^ ((row & 7) << 4));
        *(u4*)(ptb + boff) = pk;
      }
    }
    __syncthreads();
    int prow = wid * 16 + lrow;
#pragma unroll
    for (int ks = 0; ks < 4; ++ks) {
      int t = ks * 32 + lk * 8;
      int aoff = prow * 256 + ((t * 2) ^ ((prow & 7) << 4));
      s8v af = *(const s8v*)(ptb + aoff);
#pragma unroll
      for (int nq = 0; nq < 2; ++nq) {
        s8v bf = *(const s8v*)&Vs[nq * 16 + lrow][t];
        acc[nq] = __builtin_amdgcn_mfma_f32_16x16x32_bf16(af, bf, acc[nq], 0, 0, 0);
      }
    }
    __syncthreads();
  }
#pragma unroll
  for (int nq = 0; nq < 2; ++nq)
#pragma unroll
    for (int e = 0; e < 4; ++e) {
      float v = acc[nq][e];
      float ge = 0.5f * v * (1.f + erff(v * 0.70710678118654752f));
      int row = lt + wid * 16 + lk * 4 + e;
      int col = h * 32 + nq * 16 + lrow;
      g[(size_t)(b * 1024 + row) * 256 + col] = ge;
    }
}

// ---------------- K5: out = gelu(v) @ Wproj^T (fp32, small) ----------------
__global__ __launch_bounds__(256, 2) void k_proj(
    const float* __restrict__ g, const float* __restrict__ Wp,
    float* __restrict__ out) {
  __shared__ float g_s[16][68];
  __shared__ float w_s[16][68];
  int rt = blockIdx.y * 64;
  int it = blockIdx.x * 64;
  int tid = threadIdx.x;
  int tx = tid & 15, ty = tid >> 4;
  int r4 = tid >> 2, cq = tid & 3;
  float acc[4][4] = {};
  for (int kc = 0; kc < 256; kc += 16) {
    float4 gv = *(const float4*)&g[(size_t)(rt + r4) * 256 + kc + cq * 4];
    g_s[cq * 4 + 0][r4] = gv.x; g_s[cq * 4 + 1][r4] = gv.y;
    g_s[cq * 4 + 2][r4] = gv.z; g_s[cq * 4 + 3][r4] = gv.w;
    float4 wv = *(const float4*)&Wp[(size_t)(it + r4) * 256 + kc + cq * 4];
    w_s[cq * 4 + 0][r4] = wv.x; w_s[cq * 4 + 1][r4] = wv.y;
    w_s[cq * 4 + 2][r4] = wv.z; w_s[cq * 4 + 3][r4] = wv.w;
    __syncthreads();
#pragma unroll
    for (int k = 0; k < 16; ++k) {
      float4 a = *(const float4*)&g_s[k][ty * 4];
      float4 bb = *(const float4*)&w_s[k][tx * 4];
      acc[0][0] = fmaf(a.x, bb.x, acc[0][0]); acc[0][1] = fmaf(a.x, bb.y, acc[0][1]);
      acc[0][2] = fmaf(a.x, bb.z, acc[0][2]); acc[0][3] = fmaf(a.x, bb.w, acc[0][3]);
      acc[1][0] = fmaf(a.y, bb.x, acc[1][0]); acc[1][1] = fmaf(a.y, bb.y, acc[1][1]);
      acc[1][2] = fmaf(a.y, bb.z, acc[1][2]); acc[1][3] = fmaf(a.y, bb.w, acc[1][3]);
      acc[2][0] = fmaf(a.z, bb.x, acc[2][0]); acc[2][1] = fmaf(a.z, bb.y, acc[2][1]);
      acc[2][2] = fmaf(a.z, bb.z, acc[2][2]); acc[2][3] = fmaf(a.z, bb.w, acc[2][3]);
      acc[3][0] = fmaf(a.w, bb.x, acc[3][0]); acc[3][1] = fmaf(a.w, bb.y, acc[3][1]);
      acc[3][2] = fmaf(a.w, bb.z, acc[3][2]); acc[3][3] = fmaf(a.w, bb.w, acc[3][3]);
    }
    __syncthreads();
  }
#pragma unroll
  for (int i = 0; i < 4; ++i) {
    float4 o = make_float4(acc[i][0], acc[i][1], acc[i][2], acc[i][3]);
    *(float4*)&out[(size_t)(rt + ty * 4 + i) * 256 + it + tx * 4] = o;
  }
}

extern "C" void kernel_launch(void* const* d_in, const int* in_sizes, int n_in,
                              void* d_out, int out_size, void* d_ws, size_t ws_size,
                              hipStream_t stream) {
  const float* x   = (const float*)d_in[0];
  const int*   adj = (const int*)d_in[1];
  const float* Wq  = (const float*)d_in[3];
  const float* Wk  = (const float*)d_in[4];
  const float* Wv  = (const float*)d_in[5];
  const float* Lam = (const float*)d_in[6];
  const float* Wp  = (const float*)d_in[7];

  float* out  = (float*)d_out;                 // [8,1024,256]
  float* attn = out + (size_t)BB * TT * 256;   // [8,8,1024,1024]

  const size_t SZ = (size_t)8 * 1024 * 256;    // 2097152 elements
  char* base = (char*)d_ws;
  ushort* xTqhi = (ushort*)(base + 0 * SZ * 2);
  ushort* xTqlo = (ushort*)(base + 1 * SZ * 2);
  ushort* xTkhi = (ushort*)(base + 2 * SZ * 2);
  ushort* xTklo = (ushort*)(base + 3 * SZ * 2);
  ushort* vT    = (ushort*)(base + 4 * SZ * 2);
  ushort* qhi   = (ushort*)(base + 5 * SZ * 2);
  ushort* qlo   = (ushort*)(base + 6 * SZ * 2);
  ushort* khi   = (ushort*)(base + 7 * SZ * 2);
  ushort* klo   = (ushort*)(base + 8 * SZ * 2);
  float*  gbuf  = (float*)(base + 9 * SZ * 2);          // SZ floats (8 MB)
  float*  pm    = (float*)(base + 9 * SZ * 2 + SZ * 4); // 512K floats
  float*  ps    = pm + 524288;
  float*  fmb   = ps + 524288;                           // 65536 floats
  float*  frb   = fmb + 65536;

  k_xw<<<512, 256, 0, stream>>>(x, Wq, Wk, Wv, xTqhi, xTqlo, xTkhi, xTklo, vT);
  k_gcn<<<512, 256, 0, stream>>>(adj, xTqhi, xTqlo, xTkhi, xTklo, qhi, qlo, khi, klo);
  k_stats<<<2048, 256, 0, stream>>>(qhi, qlo, khi, klo, adj, Lam, pm, ps);
  k_reduce<<<256, 256, 0, stream>>>(pm, ps, fmb, frb);
  k_final<<<2048, 256, 0, stream>>>(qhi, qlo, khi, klo, adj, Lam, fmb, frb, attn);
  k_pv<<<1024, 256, 0, stream>>>(attn, vT, gbuf);
  k_proj<<<dim3(4, 128), 256, 0, stream>>>(gbuf, Wp, out);
}

// Round 12
// 424.070 us; speedup vs baseline: 1.0751x; 1.0751x over previous
//
#include <hip/hip_runtime.h>
#include <cmath>

#define TT 1024
#define BB 8

typedef __attribute__((ext_vector_type(4))) float f4;
typedef __attribute__((ext_vector_type(4))) unsigned int u4;
typedef __attribute__((ext_vector_type(8))) short s8v;

__device__ __forceinline__ ushort f2bf(float x) {
  unsigned u = __builtin_bit_cast(unsigned, x);
  unsigned r = (u + 0x7FFFu + ((u >> 16) & 1u)) >> 16;
  return (ushort)r;
}
__device__ __forceinline__ float bf2f(ushort b) {
  unsigned u = ((unsigned)b) << 16;
  return __builtin_bit_cast(float, u);
}
__device__ __forceinline__ void st8(ushort* p, const ushort* v) {
  u4 w;
  w.x = (unsigned)v[0] | ((unsigned)v[1] << 16);
  w.y = (unsigned)v[2] | ((unsigned)v[3] << 16);
  w.z = (unsigned)v[4] | ((unsigned)v[5] << 16);
  w.w = (unsigned)v[6] | ((unsigned)v[7] << 16);
  *(u4*)p = w;
}

// ---------------- K1: x @ {Wq/16, Wk, Wv} -> transposed bf16 hi/lo + vT ----------------
__global__ __launch_bounds__(256, 2) void k_xw(
    const float* __restrict__ x, const float* __restrict__ Wq,
    const float* __restrict__ Wk, const float* __restrict__ Wv,
    ushort* __restrict__ xTqhi, ushort* __restrict__ xTqlo,
    ushort* __restrict__ xTkhi, ushort* __restrict__ xTklo,
    ushort* __restrict__ vT) {
  __shared__ float xs[16][256];
  int bid = blockIdx.x;
  int b = bid & 7, t0 = (bid >> 3) * 16;
  int tid = threadIdx.x;
#pragma unroll
  for (int i = 0; i < 4; ++i) {
    int e = i * 256 + tid;
    int t = e >> 6, c4 = (e & 63) * 4;
    *(f4*)&xs[t][c4] = *(const f4*)&x[((size_t)(b * 1024 + t0 + t)) * 256 + c4];
  }
  int c = tid, h = c >> 5, d = c & 31;
  float wqr[32], wkr[32], wvr[32];
#pragma unroll
  for (int e = 0; e < 32; ++e) {
    wqr[e] = Wq[e * 32 + d] * 0.0625f;  // fold scale = dim^-0.5 = 1/16 into Wq
    wkr[e] = Wk[e * 32 + d];
    wvr[e] = Wv[e * 32 + d];
  }
  __syncthreads();
  size_t rowq = ((size_t)(b * 256 + c)) * 1024 + t0;
#pragma unroll
  for (int tg = 0; tg < 2; ++tg) {
    ushort qh[8], ql[8], kh[8], kl[8], vh[8];
#pragma unroll
    for (int tt = 0; tt < 8; ++tt) {
      int t = tg * 8 + tt;
      float aq = 0.f, ak = 0.f, av = 0.f;
#pragma unroll
      for (int e = 0; e < 32; ++e) {
        float xe = xs[t][h * 32 + e];
        aq = fmaf(xe, wqr[e], aq);
        ak = fmaf(xe, wkr[e], ak);
        av = fmaf(xe, wvr[e], av);
      }
      ushort hq = f2bf(aq); qh[tt] = hq; ql[tt] = f2bf(aq - bf2f(hq));
      ushort hk = f2bf(ak); kh[tt] = hk; kl[tt] = f2bf(ak - bf2f(hk));
      vh[tt] = f2bf(av);
    }
    st8(xTqhi + rowq + tg * 8, qh);
    st8(xTqlo + rowq + tg * 8, ql);
    st8(xTkhi + rowq + tg * 8, kh);
    st8(xTklo + rowq + tg * 8, kl);
    st8(vT    + rowq + tg * 8, vh);
  }
}

// ---------------- K2: GCN [q|k] = adj @ [xq|xk] via MFMA, grid 512 ----------------
__global__ __launch_bounds__(256, 2) void k_gcn(
    const int* __restrict__ adj,
    const ushort* __restrict__ xTqhi, const ushort* __restrict__ xTqlo,
    const ushort* __restrict__ xTkhi, const ushort* __restrict__ xTklo,
    ushort* __restrict__ qhi, ushort* __restrict__ qlo,
    ushort* __restrict__ khi, ushort* __restrict__ klo) {
  int bid = blockIdx.x;
  int ct = bid & 3, lt = ((bid >> 2) & 15) * 64, b = bid >> 6;
  int nt = ct >> 1, cbase = (ct & 1) * 128;
  const ushort* XH = (nt ? xTkhi : xTqhi) + (size_t)b * 256 * 1024;
  const ushort* XL = (nt ? xTklo : xTqlo) + (size_t)b * 256 * 1024;
  ushort* OH = (nt ? khi : qhi) + (size_t)b * 1024 * 256;
  ushort* OL = (nt ? klo : qlo) + (size_t)b * 1024 * 256;
  const int* AD = adj + (size_t)b * 1024 * 1024;
  int tid = threadIdx.x, wid = tid >> 6, lane = tid & 63;
  int lrow = lane & 15, lk = lane >> 4;
  int wr = wid >> 1, wc = wid & 1;
  int rbase = lt + wr * 32;
  int cb2 = cbase + wc * 64;
  f4 acc[2][4];
#pragma unroll
  for (int i = 0; i < 2; ++i)
#pragma unroll
    for (int j = 0; j < 4; ++j) acc[i][j] = (f4)(0.f);

  for (int k0 = 0; k0 < 1024; k0 += 32) {
    s8v afr[2];
#pragma unroll
    for (int rq = 0; rq < 2; ++rq) {
      const int* ap = &AD[(size_t)(rbase + rq * 16 + lrow) * 1024 + k0 + lk * 8];
      int4 a0 = *(const int4*)ap;
      int4 a1 = *(const int4*)(ap + 4);
      u4 fw;
      fw.x = (a0.x ? 0x3F80u : 0u) | (a0.y ? 0x3F800000u : 0u);
      fw.y = (a0.z ? 0x3F80u : 0u) | (a0.w ? 0x3F800000u : 0u);
      fw.z = (a1.x ? 0x3F80u : 0u) | (a1.y ? 0x3F800000u : 0u);
      fw.w = (a1.z ? 0x3F80u : 0u) | (a1.w ? 0x3F800000u : 0u);
      afr[rq] = __builtin_bit_cast(s8v, fw);
    }
#pragma unroll
    for (int nq = 0; nq < 4; ++nq) {
      int col = cb2 + nq * 16 + lrow;
      s8v bh = *(const s8v*)&XH[(size_t)col * 1024 + k0 + lk * 8];
      s8v bl = *(const s8v*)&XL[(size_t)col * 1024 + k0 + lk * 8];
#pragma unroll
      for (int rq = 0; rq < 2; ++rq) {
        acc[rq][nq] = __builtin_amdgcn_mfma_f32_16x16x32_bf16(afr[rq], bh, acc[rq][nq], 0, 0, 0);
        acc[rq][nq] = __builtin_amdgcn_mfma_f32_16x16x32_bf16(afr[rq], bl, acc[rq][nq], 0, 0, 0);
      }
    }
  }
#pragma unroll
  for (int rq = 0; rq < 2; ++rq)
#pragma unroll
    for (int nq = 0; nq < 4; ++nq)
#pragma unroll
      for (int e = 0; e < 4; ++e) {
        float v = acc[rq][nq][e];
        int row = rbase + rq * 16 + lk * 4 + e;
        int col = cb2 + nq * 16 + lrow;
        ushort hi = f2bf(v);
        ushort lo = f2bf(v - bf2f(hi));
        OH[(size_t)row * 256 + col] = hi;
        OL[(size_t)row * 256 + col] = lo;
      }
}

// ---------------- K3a: score stats + RAW mixed score store to attn region ----------
// grid 2048 (b x 32 row-tiles x 8 col-chunks). Identical to the validated k_stats
// plus one coalesced scalar store per (e,i2) writing the raw masked score
// (masked = -1e30f) into attn. Store addressing identical to old k_final's.
__global__ __launch_bounds__(256, 2) void k_stats_w(
    const ushort* __restrict__ qhi, const ushort* __restrict__ qlo,
    const ushort* __restrict__ khi, const ushort* __restrict__ klo,
    const int* __restrict__ adj, const float* __restrict__ Lam,
    float* __restrict__ sout, float* __restrict__ pm, float* __restrict__ ps) {
  __shared__ float sm_m[2][32][8];
  __shared__ float sm_s[2][32][8];
  int bid = blockIdx.x;
  int b = bid >> 8;
  int lt = ((bid >> 3) & 31) << 5;
  int tc = bid & 7;
  int tid = threadIdx.x, wid = tid >> 6, lane = tid & 63;
  int lrow = lane & 15, lk = lane >> 4;
  int wr = wid >> 1, wc = wid & 1;
  const ushort* QH = qhi + (size_t)b * 1024 * 256;
  const ushort* QL = qlo + (size_t)b * 1024 * 256;
  const ushort* KH = khi + (size_t)b * 1024 * 256;
  const ushort* KL = klo + (size_t)b * 1024 * 256;
  const int* AD = adj + (size_t)b * 1024 * 1024;
  float* AT = sout + (size_t)b * 8 * 1024 * 1024;

  s8v qfh[8], qfl[8];
  int qrow = lt + wr * 16 + lrow;
#pragma unroll
  for (int h = 0; h < 8; ++h) {
    qfh[h] = *(const s8v*)&QH[(size_t)qrow * 256 + h * 32 + lk * 8];
    qfl[h] = *(const s8v*)&QL[(size_t)qrow * 256 + h * 32 + lk * 8];
  }
  float ms[4][8], ss[4][8];
#pragma unroll
  for (int e = 0; e < 4; ++e)
#pragma unroll
    for (int i2 = 0; i2 < 8; ++i2) { ms[e][i2] = -3.0e38f; ss[e][i2] = 0.f; }

  for (int it = 0; it < 4; ++it) {
    int t0 = tc * 128 + (it * 2 + wc) * 16;
    f4 acc[8];
#pragma unroll
    for (int h = 0; h < 8; ++h) {
      s8v kh = *(const s8v*)&KH[(size_t)(t0 + lrow) * 256 + h * 32 + lk * 8];
      s8v kl = *(const s8v*)&KL[(size_t)(t0 + lrow) * 256 + h * 32 + lk * 8];
      f4 a = (f4)(0.f);
      a = __builtin_amdgcn_mfma_f32_16x16x32_bf16(qfh[h], kh, a, 0, 0, 0);
      a = __builtin_amdgcn_mfma_f32_16x16x32_bf16(qfh[h], kl, a, 0, 0, 0);
      a = __builtin_amdgcn_mfma_f32_16x16x32_bf16(qfl[h], kh, a, 0, 0, 0);
      acc[h] = a;
    }
#pragma unroll
    for (int e = 0; e < 4; ++e) {
      int row = lt + wr * 16 + lk * 4 + e;
      int a = AD[(size_t)row * 1024 + t0 + lrow];
      bool pred = a > 0;
      float raw[8];
#pragma unroll
      for (int h = 0; h < 8; ++h) { float v = acc[h][e]; raw[h] = fmaxf(v, 0.01f * v); }
#pragma unroll
      for (int i2 = 0; i2 < 8; ++i2) {
        float s = 0.f;
#pragma unroll
        for (int j = 0; j < 8; ++j) s = fmaf(Lam[i2 * 8 + j], raw[j], s);
        AT[((size_t)i2 * 1024 + row) * 1024 + t0 + lrow] = pred ? s : -1.0e30f;
        float d = s - ms[e][i2];
        float ex = __expf(fminf(d, -d));
        float snew = (d > 0.f) ? fmaf(ss[e][i2], ex, 1.f) : (ss[e][i2] + ex);
        float mnew = fmaxf(ms[e][i2], s);
        if (pred) { ss[e][i2] = snew; ms[e][i2] = mnew; }
      }
    }
  }
  // reduce across the 16 col-lanes (bits 0..3 of lane)
#pragma unroll
  for (int e = 0; e < 4; ++e)
#pragma unroll
    for (int i2 = 0; i2 < 8; ++i2) {
      float mm = ms[e][i2], sv = ss[e][i2];
      for (int off = 1; off < 16; off <<= 1) {
        float om = __shfl_xor(mm, off, 64);
        float os = __shfl_xor(sv, off, 64);
        float d = mm - om;
        float ex = __expf(fminf(d, -d));
        float sA = fmaf(os, ex, sv);
        float sB = fmaf(sv, ex, os);
        sv = (d >= 0.f) ? sA : sB;
        mm = fmaxf(mm, om);
      }
      ms[e][i2] = mm; ss[e][i2] = sv;
    }
  if (lrow == 0) {
#pragma unroll
    for (int e = 0; e < 4; ++e)
#pragma unroll
      for (int i2 = 0; i2 < 8; ++i2) {
        sm_m[wc][wr * 16 + lk * 4 + e][i2] = ms[e][i2];
        sm_s[wc][wr * 16 + lk * 4 + e][i2] = ss[e][i2];
      }
  }
  __syncthreads();
  {
    int rw = tid >> 3, i2 = tid & 7;
    float m0 = sm_m[0][rw][i2], m1 = sm_m[1][rw][i2];
    float s0 = sm_s[0][rw][i2], s1 = sm_s[1][rw][i2];
    float M = fmaxf(m0, m1);
    float S = s0 * __expf(m0 - M) + s1 * __expf(m1 - M);
    size_t R = ((size_t)(b * 8 + i2) * 1024 + lt + rw);
    pm[R * 8 + tc] = M;
    ps[R * 8 + tc] = S;
  }
}

// ---------------- K3b: reduce 8 chunk-partials -> (m, 1/sum) per row ----------------
__global__ __launch_bounds__(256) void k_reduce(
    const float* __restrict__ pm, const float* __restrict__ ps,
    float* __restrict__ fm, float* __restrict__ fr) {
  int R = blockIdx.x * 256 + threadIdx.x;   // 65536 rows
  f4 m0 = *(const f4*)&pm[(size_t)R * 8];
  f4 m1 = *(const f4*)&pm[(size_t)R * 8 + 4];
  f4 s0 = *(const f4*)&ps[(size_t)R * 8];
  f4 s1 = *(const f4*)&ps[(size_t)R * 8 + 4];
  float M = fmaxf(fmaxf(fmaxf(m0.x, m0.y), fmaxf(m0.z, m0.w)),
                  fmaxf(fmaxf(m1.x, m1.y), fmaxf(m1.z, m1.w)));
  float S = s0.x * __expf(m0.x - M) + s0.y * __expf(m0.y - M) +
            s0.z * __expf(m0.z - M) + s0.w * __expf(m0.w - M) +
            s1.x * __expf(m1.x - M) + s1.y * __expf(m1.y - M) +
            s1.z * __expf(m1.z - M) + s1.w * __expf(m1.w - M);
  fm[R] = M;
  fr[R] = 1.f / S;
}

// ---------------- K4: in-place softmax finalize + PV MFMA + GELU -> g ----------------
// Reads raw scores from attn, writes final p back (in place), then PV.
// Masked entries are -1e30 -> __expf underflows to exact 0; no adj re-read.
__global__ __launch_bounds__(256, 4) void k_pv_fin(
    float* __restrict__ attn, const ushort* __restrict__ vT,
    const float* __restrict__ fm, const float* __restrict__ fr,
    float* __restrict__ g) {
  __shared__ ushort Vs[32][136];
  __shared__ unsigned pt[64 * 128 / 2];
  int bid = blockIdx.x;
  int b = bid & 7, h = (bid >> 3) & 7, lt = (bid >> 6) * 64;
  int tid = threadIdx.x, wid = tid >> 6, lane = tid & 63;
  int lrow = lane & 15, lk = lane >> 4;
  float* AT = attn + ((size_t)(b * 8 + h) * 1024 + lt) * 1024;
  const ushort* VTb = vT + (size_t)(b * 256 + h * 32) * 1024;
  char* ptb = (char*)pt;
  int srow = tid >> 2, tq = (tid & 3) * 32;
  size_t ridx0 = (size_t)(b * 8 + h) * 1024 + lt;
  float mm = fm[ridx0 + srow];
  float rr = fr[ridx0 + srow];
  f4 acc[2];
  acc[0] = (f4)(0.f); acc[1] = (f4)(0.f);

  for (int tc = 0; tc < 1024; tc += 128) {
    {
      int col = tid >> 3, toff = (tid & 7) * 16;
      u4 v0 = *(const u4*)&VTb[(size_t)col * 1024 + tc + toff];
      u4 v1 = *(const u4*)&VTb[(size_t)col * 1024 + tc + toff + 8];
      *(u4*)&Vs[col][toff] = v0;
      *(u4*)&Vs[col][toff + 8] = v1;
    }
    {
      float* src = &AT[(size_t)srow * 1024 + tc + tq];
#pragma unroll
      for (int i = 0; i < 4; ++i) {
        f4 p0 = *(const f4*)&src[i * 8];
        f4 p1 = *(const f4*)&src[i * 8 + 4];
#pragma unroll
        for (int q = 0; q < 4; ++q) {
          p0[q] = __expf(p0[q] - mm) * rr;
          p1[q] = __expf(p1[q] - mm) * rr;
        }
        *(f4*)&src[i * 8] = p0;       // final softmax value -> attn output
        *(f4*)&src[i * 8 + 4] = p1;
        u4 pk;
        pk.x = (unsigned)f2bf(p0[0]) | ((unsigned)f2bf(p0[1]) << 16);
        pk.y = (unsigned)f2bf(p0[2]) | ((unsigned)f2bf(p0[3]) << 16);
        pk.z = (unsigned)f2bf(p1[0]) | ((unsigned)f2bf(p1[1]) << 16);
        pk.w = (unsigned)f2bf(p1[2]) | ((unsigned)f2bf(p1[3]) << 16);
        int t = tq + i * 8;
        int boff = srow * 256 + ((t * 2) ^ ((srow & 7) << 4));
        *(u4*)(ptb + boff) = pk;
      }
    }
    __syncthreads();
    int prow = wid * 16 + lrow;
#pragma unroll
    for (int ks = 0; ks < 4; ++ks) {
      int t = ks * 32 + lk * 8;
      int aoff = prow * 256 + ((t * 2) ^ ((prow & 7) << 4));
      s8v af = *(const s8v*)(ptb + aoff);
#pragma unroll
      for (int nq = 0; nq < 2; ++nq) {
        s8v bf = *(const s8v*)&Vs[nq * 16 + lrow][t];
        acc[nq] = __builtin_amdgcn_mfma_f32_16x16x32_bf16(af, bf, acc[nq], 0, 0, 0);
      }
    }
    __syncthreads();
  }
#pragma unroll
  for (int nq = 0; nq < 2; ++nq)
#pragma unroll
    for (int e = 0; e < 4; ++e) {
      float v = acc[nq][e];
      float ge = 0.5f * v * (1.f + erff(v * 0.70710678118654752f));
      int row = lt + wid * 16 + lk * 4 + e;
      int col = h * 32 + nq * 16 + lrow;
      g[(size_t)(b * 1024 + row) * 256 + col] = ge;
    }
}

// ---------------- K5: out = gelu(v) @ Wproj^T (fp32, small) ----------------
__global__ __launch_bounds__(256, 2) void k_proj(
    const float* __restrict__ g, const float* __restrict__ Wp,
    float* __restrict__ out) {
  __shared__ float g_s[16][68];
  __shared__ float w_s[16][68];
  int rt = blockIdx.y * 64;
  int it = blockIdx.x * 64;
  int tid = threadIdx.x;
  int tx = tid & 15, ty = tid >> 4;
  int r4 = tid >> 2, cq = tid & 3;
  float acc[4][4] = {};
  for (int kc = 0; kc < 256; kc += 16) {
    float4 gv = *(const float4*)&g[(size_t)(rt + r4) * 256 + kc + cq * 4];
    g_s[cq * 4 + 0][r4] = gv.x; g_s[cq * 4 + 1][r4] = gv.y;
    g_s[cq * 4 + 2][r4] = gv.z; g_s[cq * 4 + 3][r4] = gv.w;
    float4 wv = *(const float4*)&Wp[(size_t)(it + r4) * 256 + kc + cq * 4];
    w_s[cq * 4 + 0][r4] = wv.x; w_s[cq * 4 + 1][r4] = wv.y;
    w_s[cq * 4 + 2][r4] = wv.z; w_s[cq * 4 + 3][r4] = wv.w;
    __syncthreads();
#pragma unroll
    for (int k = 0; k < 16; ++k) {
      float4 a = *(const float4*)&g_s[k][ty * 4];
      float4 bb = *(const float4*)&w_s[k][tx * 4];
      acc[0][0] = fmaf(a.x, bb.x, acc[0][0]); acc[0][1] = fmaf(a.x, bb.y, acc[0][1]);
      acc[0][2] = fmaf(a.x, bb.z, acc[0][2]); acc[0][3] = fmaf(a.x, bb.w, acc[0][3]);
      acc[1][0] = fmaf(a.y, bb.x, acc[1][0]); acc[1][1] = fmaf(a.y, bb.y, acc[1][1]);
      acc[1][2] = fmaf(a.y, bb.z, acc[1][2]); acc[1][3] = fmaf(a.y, bb.w, acc[1][3]);
      acc[2][0] = fmaf(a.z, bb.x, acc[2][0]); acc[2][1] = fmaf(a.z, bb.y, acc[2][1]);
      acc[2][2] = fmaf(a.z, bb.z, acc[2][2]); acc[2][3] = fmaf(a.z, bb.w, acc[2][3]);
      acc[3][0] = fmaf(a.w, bb.x, acc[3][0]); acc[3][1] = fmaf(a.w, bb.y, acc[3][1]);
      acc[3][2] = fmaf(a.w, bb.z, acc[3][2]); acc[3][3] = fmaf(a.w, bb.w, acc[3][3]);
    }
    __syncthreads();
  }
#pragma unroll
  for (int i = 0; i < 4; ++i) {
    float4 o = make_float4(acc[i][0], acc[i][1], acc[i][2], acc[i][3]);
    *(float4*)&out[(size_t)(rt + ty * 4 + i) * 256 + it + tx * 4] = o;
  }
}

extern "C" void kernel_launch(void* const* d_in, const int* in_sizes, int n_in,
                              void* d_out, int out_size, void* d_ws, size_t ws_size,
                              hipStream_t stream) {
  const float* x   = (const float*)d_in[0];
  const int*   adj = (const int*)d_in[1];
  const float* Wq  = (const float*)d_in[3];
  const float* Wk  = (const float*)d_in[4];
  const float* Wv  = (const float*)d_in[5];
  const float* Lam = (const float*)d_in[6];
  const float* Wp  = (const float*)d_in[7];

  float* out  = (float*)d_out;                 // [8,1024,256]
  float* attn = out + (size_t)BB * TT * 256;   // [8,8,1024,1024]

  const size_t SZ = (size_t)8 * 1024 * 256;    // 2097152 elements
  char* base = (char*)d_ws;
  ushort* xTqhi = (ushort*)(base + 0 * SZ * 2);
  ushort* xTqlo = (ushort*)(base + 1 * SZ * 2);
  ushort* xTkhi = (ushort*)(base + 2 * SZ * 2);
  ushort* xTklo = (ushort*)(base + 3 * SZ * 2);
  ushort* vT    = (ushort*)(base + 4 * SZ * 2);
  ushort* qhi   = (ushort*)(base + 5 * SZ * 2);
  ushort* qlo   = (ushort*)(base + 6 * SZ * 2);
  ushort* khi   = (ushort*)(base + 7 * SZ * 2);
  ushort* klo   = (ushort*)(base + 8 * SZ * 2);
  float*  gbuf  = (float*)(base + 9 * SZ * 2);          // SZ floats (8 MB)
  float*  pm    = (float*)(base + 9 * SZ * 2 + SZ * 4); // 512K floats
  float*  ps    = pm + 524288;
  float*  fmb   = ps + 524288;                           // 65536 floats
  float*  frb   = fmb + 65536;

  k_xw<<<512, 256, 0, stream>>>(x, Wq, Wk, Wv, xTqhi, xTqlo, xTkhi, xTklo, vT);
  k_gcn<<<512, 256, 0, stream>>>(adj, xTqhi, xTqlo, xTkhi, xTklo, qhi, qlo, khi, klo);
  k_stats_w<<<2048, 256, 0, stream>>>(qhi, qlo, khi, klo, adj, Lam, attn, pm, ps);
  k_reduce<<<256, 256, 0, stream>>>(pm, ps, fmb, frb);
  k_pv_fin<<<1024, 256, 0, stream>>>(attn, vT, fmb, frb, gbuf);
  k_proj<<<dim3(4, 128), 256, 0, stream>>>(gbuf, Wp, out);
}